// Round 5
// baseline (240.413 us; speedup 1.0000x reference)
//
#include <hip/hip_runtime.h>
#include <hip/hip_bf16.h>

// Problem constants: T=1024, B=2, E=1024, H=16, D=64, R=2*T-1
#define TT 1024
#define BB 2
#define EE 1024
#define HH 16
#define DD 64
#define RR 2047
#define TB (TT * BB)   // 2048
#define E3 (3 * EE)    // 3072

typedef __attribute__((ext_vector_type(4))) float f32x4;
typedef __attribute__((ext_vector_type(8))) short s16x8;

static __device__ __forceinline__ short f2bf(float x) {
  unsigned u = __builtin_bit_cast(unsigned, x);
  unsigned r = (u + 0x7FFFu + ((u >> 16) & 1u)) >> 16;
  return (short)r;
}
static __device__ __forceinline__ float bf2f(short x) {
  unsigned u = ((unsigned)(unsigned short)x) << 16;
  return __builtin_bit_cast(float, u);
}
static __device__ __forceinline__ float bperm(int idx, float v) {
  return __builtin_bit_cast(float,
      __builtin_amdgcn_ds_bpermute(idx, __builtin_bit_cast(int, v)));
}

// ---------------------------------------------------------------------------
// Fused fp32 -> bf16 convert for all 5 tensors (one launch).
// Segments (elements): x 2M | in_w 3M | pos 2M (src RR*EE, zero-pad) |
//                      pos_w 1M | out_w 1M.   8 elems/thread.
// ---------------------------------------------------------------------------
__global__ __launch_bounds__(256) void cvt_all(
    const float* __restrict__ x, const float* __restrict__ in_w,
    const float* __restrict__ pos, const float* __restrict__ pos_w,
    const float* __restrict__ out_w,
    short* __restrict__ xb, short* __restrict__ inwb, short* __restrict__ posb,
    short* __restrict__ poswb, short* __restrict__ outwb) {
  const long M1 = 1 << 20;
  long off = (long)(blockIdx.x * 256 + threadIdx.x) * 8;
  const float* src; short* dst; long nsrc;
  if (off < 2 * M1)      { src = x;     dst = xb;    nsrc = 2 * M1; }
  else if (off < 5 * M1) { off -= 2 * M1; src = in_w;  dst = inwb;  nsrc = 3 * M1; }
  else if (off < 7 * M1) { off -= 5 * M1; src = pos;   dst = posb;  nsrc = (long)RR * EE; }
  else if (off < 8 * M1) { off -= 7 * M1; src = pos_w; dst = poswb; nsrc = M1; }
  else                   { off -= 8 * M1; src = out_w; dst = outwb; nsrc = M1; }
  s16x8 o;
  if (off + 8 <= nsrc) {   // RR*EE is 8-divisible -> chunks fully in or out
    f32x4 a = *(const f32x4*)&src[off];
    f32x4 c = *(const f32x4*)&src[off + 4];
    #pragma unroll
    for (int j = 0; j < 4; ++j) { o[j] = f2bf(a[j]); o[4 + j] = f2bf(c[j]); }
  } else {
    #pragma unroll
    for (int j = 0; j < 8; ++j) o[j] = 0;
  }
  *(s16x8*)&dst[off] = o;
}

// ---------------------------------------------------------------------------
// bf16 MFMA GEMM (m97 structure): C[M,N] = A[M,K] @ W[N,K]^T + bias[N]
// ---------------------------------------------------------------------------
#define GBM 128
#define GBN 128
#define GBK 32

template <int OUT_BF16>
__global__ __launch_bounds__(256) void gemm_bf16_mfma(
    const short* __restrict__ A, const short* __restrict__ W,
    const float* __restrict__ bias, void* __restrict__ Cout,
    int M, int N, int K) {
  __shared__ __align__(16) short lA[2][GBM * GBK];
  __shared__ __align__(16) short lB[2][GBN * GBK];

  const int tid = threadIdx.x;
  const int lane = tid & 63;
  const int wv = tid >> 6;
  const int g = lane >> 4, cc = lane & 15;
  const int wr = wv >> 1, wc = wv & 1;
  const int m0 = blockIdx.y * GBM, n0 = blockIdx.x * GBN;

  f32x4 acc[4][4];
  #pragma unroll
  for (int i = 0; i < 4; ++i)
    #pragma unroll
    for (int j = 0; j < 4; ++j) acc[i][j] = (f32x4){0.f, 0.f, 0.f, 0.f};

#define STAGE_TILE(kk_, buf_)                                                  \
  {                                                                            \
    _Pragma("unroll")                                                          \
    for (int s = 0; s < 2; ++s) {                                              \
      int c = s * 256 + tid;                                                   \
      int row = c >> 2, slot = c & 3;                                          \
      int k8 = slot ^ (row & 3);                                               \
      __builtin_amdgcn_global_load_lds(                                        \
          (const __attribute__((address_space(1))) void*)(A + (size_t)(m0 + row) * K + (kk_) + k8 * 8), \
          (__attribute__((address_space(3))) void*)&lA[buf_][c * 8], 16, 0, 0);\
      __builtin_amdgcn_global_load_lds(                                        \
          (const __attribute__((address_space(1))) void*)(W + (size_t)(n0 + row) * K + (kk_) + k8 * 8), \
          (__attribute__((address_space(3))) void*)&lB[buf_][c * 8], 16, 0, 0);\
    }                                                                          \
  }

  int cur = 0;
  const int nt = K / GBK;
  STAGE_TILE(0, 0);

  #pragma unroll 1
  for (int t = 0; t < nt; ++t) {
    __syncthreads();
    if (t + 1 < nt) STAGE_TILE((t + 1) * GBK, cur ^ 1);

    s16x8 af[4], bf[4];
    #pragma unroll
    for (int mt = 0; mt < 4; ++mt) {
      int row = 64 * wr + 16 * mt + cc;
      af[mt] = *(const s16x8*)&lA[cur][row * GBK + ((g ^ (row & 3)) * 8)];
    }
    #pragma unroll
    for (int ntc = 0; ntc < 4; ++ntc) {
      int col = 64 * wc + 16 * ntc + cc;
      bf[ntc] = *(const s16x8*)&lB[cur][col * GBK + ((g ^ (col & 3)) * 8)];
    }
    #pragma unroll
    for (int mt = 0; mt < 4; ++mt)
      #pragma unroll
      for (int ntc = 0; ntc < 4; ++ntc)
        acc[mt][ntc] = __builtin_amdgcn_mfma_f32_16x16x32_bf16(
            af[mt], bf[ntc], acc[mt][ntc], 0, 0, 0);
    cur ^= 1;
  }
#undef STAGE_TILE

  #pragma unroll
  for (int ntc = 0; ntc < 4; ++ntc) {
    int col = n0 + 64 * wc + 16 * ntc + cc;
    float bv = bias[col];
    #pragma unroll
    for (int mt = 0; mt < 4; ++mt)
      #pragma unroll
      for (int r = 0; r < 4; ++r) {
        int rowg = m0 + 64 * wr + 16 * mt + 4 * g + r;
        float val = acc[mt][ntc][r] + bv;
        if (OUT_BF16)
          ((short*)Cout)[(size_t)rowg * N + col] = f2bf(val);
        else
          ((float*)Cout)[(size_t)rowg * N + col] = val;
      }
  }
}

// ---------------------------------------------------------------------------
// MFMA flash attention, 4-way key split per block:
//   grid (T/16=64, B*H=32); 4 waves/block; all waves share 16 q-rows; wave w
//   owns keys [256w, 256w+256) (8 tiles of 32) with private online softmax;
//   4-partial merge via LDS at the end (one barrier total).
//   K and p-band B-fragments read directly from global (16-lane x 64B rows,
//   L2-served). V staged in wave-private LDS (transpose access).
//   score[i,j] = qw_i.k_j + qr_i.p[j-i+1023]  (1/8 scale folded in)
//   BD: Btilde[ii][u] = qr_i . p[gmin+u], u = jj-ii+15 in [0,46];
//       gather via ds_bpermute (source lane (g<<4)|((cc+15-ii)&15),
//       register bt[ct + (usub>>4)][r]) — no LDS round-trip.
// LDS arena (23040 B):
//   sV[w]  = arena + w*4352          : short[32][68]     (loop)
//   sML    = arena + 17408           : float[4][2][16]   (merge)
//   sPm[w] = arena + 17920 + w*1280  : short[16][40]     (loop)
//   sO[w]  = arena + w*4352          : float[16][68]     (merge; aliases sV)
// ---------------------------------------------------------------------------
#define QB 16

__global__ __launch_bounds__(256, 7) void rel_attn_mfma3(
    const short* __restrict__ qkvb,  // [TB][3E] bf16
    const short* __restrict__ pb,    // [2048][E] bf16 (row 2047 zeroed)
    const float* __restrict__ rwb,   // [H*D]
    const float* __restrict__ rrb,   // [H*D]
    short* __restrict__ ctxb) {      // [TB][E] bf16
  __shared__ __align__(16) char arena[23040];

  const int tid = threadIdx.x;
  const int wv = tid >> 6;
  const int lane = tid & 63;
  const int g = lane >> 4;      // 0..3
  const int cc = lane & 15;     // 0..15
  const int iq0 = blockIdx.x * QB;
  const int bh = blockIdx.y;
  const int b = bh >> 4, h = bh & 15;
  const int hoff = h * DD;

  short* sV  = (short*)(arena + wv * 4352);            // [32][68]
  short* sPm = (short*)(arena + 17920 + wv * 1280);    // [16][40]

  // ---- Q fragments: row = cc (q row iq0+cc), k-pack d = 32*kh + 8*g ----
  s16x8 qw[2], qr[2];
  #pragma unroll
  for (int kh = 0; kh < 2; ++kh) {
    const int d0 = 32 * kh + 8 * g;
    const short* qp = qkvb + (size_t)((iq0 + cc) * BB + b) * E3 + hoff + d0;
    const float* rw = rwb + hoff + d0;
    const float* rr = rrb + hoff + d0;
    s16x8 qv = *(const s16x8*)qp;
    #pragma unroll
    for (int j = 0; j < 8; ++j) {
      float q = bf2f(qv[j]);
      qw[kh][j] = f2bf((q + rw[j]) * 0.125f);
      qr[kh][j] = f2bf((q + rr[j]) * 0.125f);
    }
  }

  f32x4 O[4];
  #pragma unroll
  for (int dt = 0; dt < 4; ++dt) O[dt] = (f32x4){0.f, 0.f, 0.f, 0.f};
  float mrun[4], lrun[4];
  #pragma unroll
  for (int r = 0; r < 4; ++r) { mrun[r] = -1e30f; lrun[r] = 0.f; }

  #pragma unroll 1
  for (int t = 0; t < 8; ++t) {
    const int j0 = (8 * wv + t) * 32;     // this wave's key tile base

    // ---- stage V tile [32][64] -> sV [32][68] (wave-private) ----
    #pragma unroll
    for (int c = 0; c < 4; ++c) {
      int id = c * 64 + lane;
      int row = id >> 3, c8 = id & 7;
      const short* src = qkvb + (size_t)((j0 + row) * BB + b) * E3 + 2 * EE + hoff + c8 * 8;
      *(s16x8*)&sV[row * 68 + c8 * 8] = *(const s16x8*)src;
    }

    // ---- AC: S[ct] = qw . K^T, K fragments direct from global ----
    s16x8 kf[2][2];
    #pragma unroll
    for (int ct = 0; ct < 2; ++ct)
      #pragma unroll
      for (int kh = 0; kh < 2; ++kh)
        kf[ct][kh] = *(const s16x8*)(qkvb + (size_t)((j0 + 16 * ct + cc) * BB + b) * E3 + EE + hoff + 32 * kh + 8 * g);

    f32x4 S[2];
    #pragma unroll
    for (int ct = 0; ct < 2; ++ct) {
      S[ct] = (f32x4){0.f, 0.f, 0.f, 0.f};
      #pragma unroll
      for (int kh = 0; kh < 2; ++kh)
        S[ct] = __builtin_amdgcn_mfma_f32_16x16x32_bf16(qw[kh], kf[ct][kh], S[ct], 0, 0, 0);
    }

    // ---- BD: Btilde = qr . pband^T (3 ut tiles), band direct from global ----
    const int gmin = j0 - iq0 + 1008;
    f32x4 bt[3];
    #pragma unroll
    for (int ut = 0; ut < 3; ++ut) {
      const int prl = gmin + 16 * ut + cc;   // <= 2047 (row 2047 is zeros)
      bt[ut] = (f32x4){0.f, 0.f, 0.f, 0.f};
      #pragma unroll
      for (int kh = 0; kh < 2; ++kh) {
        s16x8 pf = *(const s16x8*)(pb + (size_t)prl * EE + hoff + 32 * kh + 8 * g);
        bt[ut] = __builtin_amdgcn_mfma_f32_16x16x32_bf16(qr[kh], pf, bt[ut], 0, 0, 0);
      }
    }
    // gather: S[ct][r] += Btilde[ii=4g+r][16ct + cc+15-ii] via bpermute.
    // source lane = (g<<4)|((cc+15-ii)&15); reg = bt[ct + (usub>=16)][r].
    #pragma unroll
    for (int r = 0; r < 4; ++r) {
      const int usub = cc + 15 - 4 * g - r;            // 0..30
      const int idx = (((lane & 48)) | (usub & 15)) << 2;
      const float va = bperm(idx, bt[0][r]);
      const float vb = bperm(idx, bt[1][r]);
      const float vc = bperm(idx, bt[2][r]);
      const bool hi = usub >= 16;
      S[0][r] += hi ? vb : va;
      S[1][r] += hi ? vc : vb;
    }

    // ---- online softmax (rows = 4g+r, cols spread over cc and ct) ----
    float mx[4];
    #pragma unroll
    for (int r = 0; r < 4; ++r) mx[r] = fmaxf(S[0][r], S[1][r]);
    #pragma unroll
    for (int msk = 1; msk < 16; msk <<= 1)
      #pragma unroll
      for (int r = 0; r < 4; ++r) mx[r] = fmaxf(mx[r], __shfl_xor(mx[r], msk, 64));
    float f[4], sm[4];
    #pragma unroll
    for (int r = 0; r < 4; ++r) {
      float mn = fmaxf(mrun[r], mx[r]);
      f[r] = __expf(mrun[r] - mn);
      mrun[r] = mn;
      S[0][r] = __expf(S[0][r] - mn);
      S[1][r] = __expf(S[1][r] - mn);
      sm[r] = S[0][r] + S[1][r];
    }
    #pragma unroll
    for (int msk = 1; msk < 16; msk <<= 1)
      #pragma unroll
      for (int r = 0; r < 4; ++r) sm[r] += __shfl_xor(sm[r], msk, 64);
    #pragma unroll
    for (int r = 0; r < 4; ++r) lrun[r] = lrun[r] * f[r] + sm[r];
    #pragma unroll
    for (int dt = 0; dt < 4; ++dt)
      #pragma unroll
      for (int r = 0; r < 4; ++r) O[dt][r] *= f[r];

    // ---- P to A-fragment layout via wave-private LDS ----
    #pragma unroll
    for (int ct = 0; ct < 2; ++ct)
      #pragma unroll
      for (int r = 0; r < 4; ++r)
        sPm[(4 * g + r) * 40 + 16 * ct + cc] = f2bf(S[ct][r]);

    s16x8 pa = *(const s16x8*)&sPm[cc * 40 + 8 * g];

    // ---- V^T fragments (scalar transpose reads) + PV ----
    s16x8 vf[4];
    #pragma unroll
    for (int dt = 0; dt < 4; ++dt)
      #pragma unroll
      for (int jj = 0; jj < 8; ++jj)
        vf[dt][jj] = sV[(8 * g + jj) * 68 + 16 * dt + cc];
    #pragma unroll
    for (int dt = 0; dt < 4; ++dt)
      O[dt] = __builtin_amdgcn_mfma_f32_16x16x32_bf16(pa, vf[dt], O[dt], 0, 0, 0);
  }

  // ---- 4-partial merge via LDS ----
  float* sOw = (float*)(arena + wv * 4352);      // [16][68], aliases own sV
  #pragma unroll
  for (int dt = 0; dt < 4; ++dt)
    #pragma unroll
    for (int r = 0; r < 4; ++r)
      sOw[(4 * g + r) * 68 + 16 * dt + cc] = O[dt][r];
  float* sML = (float*)(arena + 17408);          // [w][2][16]
  if (cc == 0) {
    #pragma unroll
    for (int r = 0; r < 4; ++r) {
      sML[wv * 32 + (4 * g + r)] = mrun[r];
      sML[wv * 32 + 16 + (4 * g + r)] = lrun[r];
    }
  }
  __syncthreads();

  const int ii = tid >> 4, ccc = tid & 15;
  float mM = sML[ii];
  #pragma unroll
  for (int w = 1; w < 4; ++w) mM = fmaxf(mM, sML[w * 32 + ii]);
  float fw[4], den = 0.f;
  #pragma unroll
  for (int w = 0; w < 4; ++w) {
    fw[w] = __expf(sML[w * 32 + ii] - mM);
    den += fw[w] * sML[w * 32 + 16 + ii];
  }
  const float rinv = 1.0f / den;
  #pragma unroll
  for (int q = 0; q < 4; ++q) {
    const int col = 16 * q + ccc;
    float acc = 0.f;
    #pragma unroll
    for (int w = 0; w < 4; ++w)
      acc += fw[w] * ((const float*)(arena + w * 4352))[ii * 68 + col];
    ctxb[(size_t)((iq0 + ii) * BB + b) * EE + hoff + col] = f2bf(acc * rinv);
  }
}

// ---------------------------------------------------------------------------
extern "C" void kernel_launch(void* const* d_in, const int* in_sizes, int n_in,
                              void* d_out, int out_size, void* d_ws, size_t ws_size,
                              hipStream_t stream) {
  const float* x      = (const float*)d_in[0];
  const float* pos    = (const float*)d_in[1];
  const float* in_w   = (const float*)d_in[2];
  const float* in_b   = (const float*)d_in[3];
  const float* pos_w  = (const float*)d_in[4];
  const float* pos_b  = (const float*)d_in[5];
  const float* out_w  = (const float*)d_in[6];
  const float* out_b  = (const float*)d_in[7];
  const float* r_w    = (const float*)d_in[8];
  const float* r_r    = (const float*)d_in[9];
  float* out = (float*)d_out;

  const size_t M1 = 1024 * 1024;
  short* xb    = (short*)d_ws;        // 2M
  short* inwb  = xb    + 2 * M1;      // 3M
  short* posb  = inwb  + 3 * M1;      // 2M (2048 rows, row 2047 zeroed)
  short* poswb = posb  + 2 * M1;      // 1M
  short* outwb = poswb + 1 * M1;      // 1M
  short* qkvb  = outwb + 1 * M1;      // 6M
  short* pb    = qkvb  + 6 * M1;      // 2M
  short* ctxb  = pb    + 2 * M1;      // 2M

  // ---- fused converts (one launch; 9M elems / 8 per thread / 256) ----
  cvt_all<<<dim3(4608), dim3(256), 0, stream>>>(
      x, in_w, pos, pos_w, out_w, xb, inwb, posb, poswb, outwb);

  gemm_bf16_mfma<1><<<dim3(E3 / GBN, TB / GBM), dim3(256), 0, stream>>>(
      xb, inwb, in_b, qkvb, TB, E3, EE);

  gemm_bf16_mfma<1><<<dim3(EE / GBN, 2048 / GBM), dim3(256), 0, stream>>>(
      posb, poswb, pos_b, pb, 2048, EE, EE);

  rel_attn_mfma3<<<dim3(TT / QB, BB * HH), dim3(256), 0, stream>>>(
      qkvb, pb, r_w, r_r, ctxb);

  gemm_bf16_mfma<0><<<dim3(EE / GBN, TB / GBM), dim3(256), 0, stream>>>(
      ctxb, outwb, out_b, out, TB, EE, EE);
}

// Round 6
// 233.656 us; speedup vs baseline: 1.0289x; 1.0289x over previous
//
#include <hip/hip_runtime.h>
#include <hip/hip_bf16.h>

// Problem constants: T=1024, B=2, E=1024, H=16, D=64, R=2*T-1
#define TT 1024
#define BB 2
#define EE 1024
#define HH 16
#define DD 64
#define RR 2047
#define TB (TT * BB)   // 2048
#define E3 (3 * EE)    // 3072

typedef __attribute__((ext_vector_type(4))) float f32x4;
typedef __attribute__((ext_vector_type(8))) short s16x8;

static __device__ __forceinline__ short f2bf(float x) {
  unsigned u = __builtin_bit_cast(unsigned, x);
  unsigned r = (u + 0x7FFFu + ((u >> 16) & 1u)) >> 16;
  return (short)r;
}
static __device__ __forceinline__ float bf2f(short x) {
  unsigned u = ((unsigned)(unsigned short)x) << 16;
  return __builtin_bit_cast(float, u);
}
static __device__ __forceinline__ float bperm(int idx, float v) {
  return __builtin_bit_cast(float,
      __builtin_amdgcn_ds_bpermute(idx, __builtin_bit_cast(int, v)));
}

// ---------------------------------------------------------------------------
// Fused fp32 -> bf16 convert for all 5 tensors (one launch).
// ---------------------------------------------------------------------------
__global__ __launch_bounds__(256) void cvt_all(
    const float* __restrict__ x, const float* __restrict__ in_w,
    const float* __restrict__ pos, const float* __restrict__ pos_w,
    const float* __restrict__ out_w,
    short* __restrict__ xb, short* __restrict__ inwb, short* __restrict__ posb,
    short* __restrict__ poswb, short* __restrict__ outwb) {
  const long M1 = 1 << 20;
  long off = (long)(blockIdx.x * 256 + threadIdx.x) * 8;
  const float* src; short* dst; long nsrc;
  if (off < 2 * M1)      { src = x;     dst = xb;    nsrc = 2 * M1; }
  else if (off < 5 * M1) { off -= 2 * M1; src = in_w;  dst = inwb;  nsrc = 3 * M1; }
  else if (off < 7 * M1) { off -= 5 * M1; src = pos;   dst = posb;  nsrc = (long)RR * EE; }
  else if (off < 8 * M1) { off -= 7 * M1; src = pos_w; dst = poswb; nsrc = M1; }
  else                   { off -= 8 * M1; src = out_w; dst = outwb; nsrc = M1; }
  s16x8 o;
  if (off + 8 <= nsrc) {
    f32x4 a = *(const f32x4*)&src[off];
    f32x4 c = *(const f32x4*)&src[off + 4];
    #pragma unroll
    for (int j = 0; j < 4; ++j) { o[j] = f2bf(a[j]); o[4 + j] = f2bf(c[j]); }
  } else {
    #pragma unroll
    for (int j = 0; j < 8; ++j) o[j] = 0;
  }
  *(s16x8*)&dst[off] = o;
}

// ---------------------------------------------------------------------------
// bf16 MFMA GEMM (m97 structure): C[M,N] = A[M,K] @ W[N,K]^T + bias[N]
// ---------------------------------------------------------------------------
#define GBM 128
#define GBN 128
#define GBK 32

template <int OUT_BF16>
__global__ __launch_bounds__(256) void gemm_bf16_mfma(
    const short* __restrict__ A, const short* __restrict__ W,
    const float* __restrict__ bias, void* __restrict__ Cout,
    int M, int N, int K) {
  __shared__ __align__(16) short lA[2][GBM * GBK];
  __shared__ __align__(16) short lB[2][GBN * GBK];

  const int tid = threadIdx.x;
  const int lane = tid & 63;
  const int wv = tid >> 6;
  const int g = lane >> 4, cc = lane & 15;
  const int wr = wv >> 1, wc = wv & 1;
  const int m0 = blockIdx.y * GBM, n0 = blockIdx.x * GBN;

  f32x4 acc[4][4];
  #pragma unroll
  for (int i = 0; i < 4; ++i)
    #pragma unroll
    for (int j = 0; j < 4; ++j) acc[i][j] = (f32x4){0.f, 0.f, 0.f, 0.f};

#define STAGE_TILE(kk_, buf_)                                                  \
  {                                                                            \
    _Pragma("unroll")                                                          \
    for (int s = 0; s < 2; ++s) {                                              \
      int c = s * 256 + tid;                                                   \
      int row = c >> 2, slot = c & 3;                                          \
      int k8 = slot ^ (row & 3);                                               \
      __builtin_amdgcn_global_load_lds(                                        \
          (const __attribute__((address_space(1))) void*)(A + (size_t)(m0 + row) * K + (kk_) + k8 * 8), \
          (__attribute__((address_space(3))) void*)&lA[buf_][c * 8], 16, 0, 0);\
      __builtin_amdgcn_global_load_lds(                                        \
          (const __attribute__((address_space(1))) void*)(W + (size_t)(n0 + row) * K + (kk_) + k8 * 8), \
          (__attribute__((address_space(3))) void*)&lB[buf_][c * 8], 16, 0, 0);\
    }                                                                          \
  }

  int cur = 0;
  const int nt = K / GBK;
  STAGE_TILE(0, 0);

  #pragma unroll 1
  for (int t = 0; t < nt; ++t) {
    __syncthreads();
    if (t + 1 < nt) STAGE_TILE((t + 1) * GBK, cur ^ 1);

    s16x8 af[4], bf[4];
    #pragma unroll
    for (int mt = 0; mt < 4; ++mt) {
      int row = 64 * wr + 16 * mt + cc;
      af[mt] = *(const s16x8*)&lA[cur][row * GBK + ((g ^ (row & 3)) * 8)];
    }
    #pragma unroll
    for (int ntc = 0; ntc < 4; ++ntc) {
      int col = 64 * wc + 16 * ntc + cc;
      bf[ntc] = *(const s16x8*)&lB[cur][col * GBK + ((g ^ (col & 3)) * 8)];
    }
    #pragma unroll
    for (int mt = 0; mt < 4; ++mt)
      #pragma unroll
      for (int ntc = 0; ntc < 4; ++ntc)
        acc[mt][ntc] = __builtin_amdgcn_mfma_f32_16x16x32_bf16(
            af[mt], bf[ntc], acc[mt][ntc], 0, 0, 0);
    cur ^= 1;
  }
#undef STAGE_TILE

  #pragma unroll
  for (int ntc = 0; ntc < 4; ++ntc) {
    int col = n0 + 64 * wc + 16 * ntc + cc;
    float bv = bias[col];
    #pragma unroll
    for (int mt = 0; mt < 4; ++mt)
      #pragma unroll
      for (int r = 0; r < 4; ++r) {
        int rowg = m0 + 64 * wr + 16 * mt + 4 * g + r;
        float val = acc[mt][ntc][r] + bv;
        if (OUT_BF16)
          ((short*)Cout)[(size_t)rowg * N + col] = f2bf(val);
        else
          ((float*)Cout)[(size_t)rowg * N + col] = val;
      }
  }
}

// ---------------------------------------------------------------------------
// MFMA flash attention, 4-way key split per block, XCD-locality version.
//   1D grid of 2048 blocks. Decode: xcd=bid&7, slot=bid>>3,
//   bh=(slot>>6)*8+xcd, qx=slot&63 — so all 64 q-blocks of one (b,h) share
//   one XCD (blockIdx%8 round-robin) and dispatch consecutively => K/V/p
//   working set (~640KB) stays hot in that XCD's 4MB L2.
//   Wave w takes key tiles 4t+w (t=0..7): block's concurrent key window is
//   one contiguous 128-key band; per-wave key sets remain disjoint (online
//   softmax is order-invariant). 4-partial merge via LDS at the end.
//   score[i,j] = qw_i.k_j + qr_i.p[j-i+1023]  (1/8 scale folded in)
//   BD gather via ds_bpermute: S[ct][r] += Btilde[ii][16ct+cc+15-ii].
// LDS arena (23040 B):
//   sV[w]  = arena + w*4352          : short[32][68]     (loop)
//   sML    = arena + 17408           : float[4][2][16]   (merge)
//   sPm[w] = arena + 17920 + w*1280  : short[16][40]     (loop)
//   sO[w]  = arena + w*4352          : float[16][68]     (merge; aliases sV)
// ---------------------------------------------------------------------------
#define QB 16

__global__ __launch_bounds__(256, 7) void rel_attn_mfma4(
    const short* __restrict__ qkvb,  // [TB][3E] bf16
    const short* __restrict__ pb,    // [2048][E] bf16 (row 2047 zeroed)
    const float* __restrict__ rwb,   // [H*D]
    const float* __restrict__ rrb,   // [H*D]
    short* __restrict__ ctxb) {      // [TB][E] bf16
  __shared__ __align__(16) char arena[23040];

  const int tid = threadIdx.x;
  const int wv = tid >> 6;
  const int lane = tid & 63;
  const int g = lane >> 4;      // 0..3
  const int cc = lane & 15;     // 0..15

  // XCD-locality decode (bijective over 2048)
  const int bid = blockIdx.x;
  const int xcd = bid & 7;
  const int slot = bid >> 3;
  const int bh = (slot >> 6) * 8 + xcd;   // 0..31; all qx of this bh share xcd
  const int qx = slot & 63;
  const int iq0 = qx * QB;
  const int b = bh >> 4, h = bh & 15;
  const int hoff = h * DD;

  short* sV  = (short*)(arena + wv * 4352);            // [32][68]
  short* sPm = (short*)(arena + 17920 + wv * 1280);    // [16][40]

  // ---- Q fragments: row = cc (q row iq0+cc), k-pack d = 32*kh + 8*g ----
  s16x8 qw[2], qr[2];
  #pragma unroll
  for (int kh = 0; kh < 2; ++kh) {
    const int d0 = 32 * kh + 8 * g;
    const short* qp = qkvb + (size_t)((iq0 + cc) * BB + b) * E3 + hoff + d0;
    const float* rw = rwb + hoff + d0;
    const float* rr = rrb + hoff + d0;
    s16x8 qv = *(const s16x8*)qp;
    #pragma unroll
    for (int j = 0; j < 8; ++j) {
      float q = bf2f(qv[j]);
      qw[kh][j] = f2bf((q + rw[j]) * 0.125f);
      qr[kh][j] = f2bf((q + rr[j]) * 0.125f);
    }
  }

  f32x4 O[4];
  #pragma unroll
  for (int dt = 0; dt < 4; ++dt) O[dt] = (f32x4){0.f, 0.f, 0.f, 0.f};
  float mrun[4], lrun[4];
  #pragma unroll
  for (int r = 0; r < 4; ++r) { mrun[r] = -1e30f; lrun[r] = 0.f; }

  #pragma unroll 1
  for (int t = 0; t < 8; ++t) {
    const int j0 = (4 * t + wv) * 32;    // interleaved: block window 128 keys

    // ---- stage V tile [32][64] -> sV [32][68] (wave-private) ----
    #pragma unroll
    for (int c = 0; c < 4; ++c) {
      int id = c * 64 + lane;
      int row = id >> 3, c8 = id & 7;
      const short* src = qkvb + (size_t)((j0 + row) * BB + b) * E3 + 2 * EE + hoff + c8 * 8;
      *(s16x8*)&sV[row * 68 + c8 * 8] = *(const s16x8*)src;
    }

    // ---- AC: S[ct] = qw . K^T, K fragments direct from global ----
    s16x8 kf[2][2];
    #pragma unroll
    for (int ct = 0; ct < 2; ++ct)
      #pragma unroll
      for (int kh = 0; kh < 2; ++kh)
        kf[ct][kh] = *(const s16x8*)(qkvb + (size_t)((j0 + 16 * ct + cc) * BB + b) * E3 + EE + hoff + 32 * kh + 8 * g);

    f32x4 S[2];
    #pragma unroll
    for (int ct = 0; ct < 2; ++ct) {
      S[ct] = (f32x4){0.f, 0.f, 0.f, 0.f};
      #pragma unroll
      for (int kh = 0; kh < 2; ++kh)
        S[ct] = __builtin_amdgcn_mfma_f32_16x16x32_bf16(qw[kh], kf[ct][kh], S[ct], 0, 0, 0);
    }

    // ---- BD: Btilde = qr . pband^T (3 ut tiles), band direct from global ----
    const int gmin = j0 - iq0 + 1008;
    f32x4 bt[3];
    #pragma unroll
    for (int ut = 0; ut < 3; ++ut) {
      const int prl = gmin + 16 * ut + cc;   // <= 2047 (row 2047 is zeros)
      bt[ut] = (f32x4){0.f, 0.f, 0.f, 0.f};
      #pragma unroll
      for (int kh = 0; kh < 2; ++kh) {
        s16x8 pf = *(const s16x8*)(pb + (size_t)prl * EE + hoff + 32 * kh + 8 * g);
        bt[ut] = __builtin_amdgcn_mfma_f32_16x16x32_bf16(qr[kh], pf, bt[ut], 0, 0, 0);
      }
    }
    // gather: S[ct][r] += Btilde[ii=4g+r][16ct + cc+15-ii] via bpermute.
    #pragma unroll
    for (int r = 0; r < 4; ++r) {
      const int usub = cc + 15 - 4 * g - r;            // 0..30
      const int idx = (((lane & 48)) | (usub & 15)) << 2;
      const float va = bperm(idx, bt[0][r]);
      const float vb = bperm(idx, bt[1][r]);
      const float vc = bperm(idx, bt[2][r]);
      const bool hi = usub >= 16;
      S[0][r] += hi ? vb : va;
      S[1][r] += hi ? vc : vb;
    }

    // ---- online softmax (rows = 4g+r, cols spread over cc and ct) ----
    float mx[4];
    #pragma unroll
    for (int r = 0; r < 4; ++r) mx[r] = fmaxf(S[0][r], S[1][r]);
    #pragma unroll
    for (int msk = 1; msk < 16; msk <<= 1)
      #pragma unroll
      for (int r = 0; r < 4; ++r) mx[r] = fmaxf(mx[r], __shfl_xor(mx[r], msk, 64));
    float f[4], sm[4];
    #pragma unroll
    for (int r = 0; r < 4; ++r) {
      float mn = fmaxf(mrun[r], mx[r]);
      f[r] = __expf(mrun[r] - mn);
      mrun[r] = mn;
      S[0][r] = __expf(S[0][r] - mn);
      S[1][r] = __expf(S[1][r] - mn);
      sm[r] = S[0][r] + S[1][r];
    }
    #pragma unroll
    for (int msk = 1; msk < 16; msk <<= 1)
      #pragma unroll
      for (int r = 0; r < 4; ++r) sm[r] += __shfl_xor(sm[r], msk, 64);
    #pragma unroll
    for (int r = 0; r < 4; ++r) lrun[r] = lrun[r] * f[r] + sm[r];
    #pragma unroll
    for (int dt = 0; dt < 4; ++dt)
      #pragma unroll
      for (int r = 0; r < 4; ++r) O[dt][r] *= f[r];

    // ---- P to A-fragment layout via wave-private LDS ----
    #pragma unroll
    for (int ct = 0; ct < 2; ++ct)
      #pragma unroll
      for (int r = 0; r < 4; ++r)
        sPm[(4 * g + r) * 40 + 16 * ct + cc] = f2bf(S[ct][r]);

    s16x8 pa = *(const s16x8*)&sPm[cc * 40 + 8 * g];

    // ---- V^T fragments (scalar transpose reads) + PV ----
    s16x8 vf[4];
    #pragma unroll
    for (int dt = 0; dt < 4; ++dt)
      #pragma unroll
      for (int jj = 0; jj < 8; ++jj)
        vf[dt][jj] = sV[(8 * g + jj) * 68 + 16 * dt + cc];
    #pragma unroll
    for (int dt = 0; dt < 4; ++dt)
      O[dt] = __builtin_amdgcn_mfma_f32_16x16x32_bf16(pa, vf[dt], O[dt], 0, 0, 0);
  }

  // ---- 4-partial merge via LDS ----
  float* sOw = (float*)(arena + wv * 4352);      // [16][68], aliases own sV
  #pragma unroll
  for (int dt = 0; dt < 4; ++dt)
    #pragma unroll
    for (int r = 0; r < 4; ++r)
      sOw[(4 * g + r) * 68 + 16 * dt + cc] = O[dt][r];
  float* sML = (float*)(arena + 17408);          // [w][2][16]
  if (cc == 0) {
    #pragma unroll
    for (int r = 0; r < 4; ++r) {
      sML[wv * 32 + (4 * g + r)] = mrun[r];
      sML[wv * 32 + 16 + (4 * g + r)] = lrun[r];
    }
  }
  __syncthreads();

  const int ii = tid >> 4, ccc = tid & 15;
  float mM = sML[ii];
  #pragma unroll
  for (int w = 1; w < 4; ++w) mM = fmaxf(mM, sML[w * 32 + ii]);
  float fw[4], den = 0.f;
  #pragma unroll
  for (int w = 0; w < 4; ++w) {
    fw[w] = __expf(sML[w * 32 + ii] - mM);
    den += fw[w] * sML[w * 32 + 16 + ii];
  }
  const float rinv = 1.0f / den;
  #pragma unroll
  for (int q = 0; q < 4; ++q) {
    const int col = 16 * q + ccc;
    float acc = 0.f;
    #pragma unroll
    for (int w = 0; w < 4; ++w)
      acc += fw[w] * ((const float*)(arena + w * 4352))[ii * 68 + col];
    ctxb[(size_t)((iq0 + ii) * BB + b) * EE + hoff + col] = f2bf(acc * rinv);
  }
}

// ---------------------------------------------------------------------------
extern "C" void kernel_launch(void* const* d_in, const int* in_sizes, int n_in,
                              void* d_out, int out_size, void* d_ws, size_t ws_size,
                              hipStream_t stream) {
  const float* x      = (const float*)d_in[0];
  const float* pos    = (const float*)d_in[1];
  const float* in_w   = (const float*)d_in[2];
  const float* in_b   = (const float*)d_in[3];
  const float* pos_w  = (const float*)d_in[4];
  const float* pos_b  = (const float*)d_in[5];
  const float* out_w  = (const float*)d_in[6];
  const float* out_b  = (const float*)d_in[7];
  const float* r_w    = (const float*)d_in[8];
  const float* r_r    = (const float*)d_in[9];
  float* out = (float*)d_out;

  const size_t M1 = 1024 * 1024;
  short* xb    = (short*)d_ws;        // 2M
  short* inwb  = xb    + 2 * M1;      // 3M
  short* posb  = inwb  + 3 * M1;      // 2M (2048 rows, row 2047 zeroed)
  short* poswb = posb  + 2 * M1;      // 1M
  short* outwb = poswb + 1 * M1;      // 1M
  short* qkvb  = outwb + 1 * M1;      // 6M
  short* pb    = qkvb  + 6 * M1;      // 2M
  short* ctxb  = pb    + 2 * M1;      // 2M

  cvt_all<<<dim3(4608), dim3(256), 0, stream>>>(
      x, in_w, pos, pos_w, out_w, xb, inwb, posb, poswb, outwb);

  gemm_bf16_mfma<1><<<dim3(E3 / GBN, TB / GBM), dim3(256), 0, stream>>>(
      xb, inwb, in_b, qkvb, TB, E3, EE);

  gemm_bf16_mfma<1><<<dim3(EE / GBN, 2048 / GBM), dim3(256), 0, stream>>>(
      posb, poswb, pos_b, pb, 2048, EE, EE);

  rel_attn_mfma4<<<dim3(2048), dim3(256), 0, stream>>>(
      qkvb, pb, r_w, r_r, ctxb);

  gemm_bf16_mfma<0><<<dim3(EE / GBN, TB / GBM), dim3(256), 0, stream>>>(
      ctxb, outwb, out_b, out, TB, EE, EE);
}

// Round 8
// 175.836 us; speedup vs baseline: 1.3673x; 1.3288x over previous
//
#include <hip/hip_runtime.h>
#include <hip/hip_bf16.h>

// Problem constants: T=1024, B=2, E=1024, H=16, D=64, R=2*T-1
#define TT 1024
#define BB 2
#define EE 1024
#define HH 16
#define DD 64
#define RR 2047
#define TB (TT * BB)   // 2048
#define E3 (3 * EE)    // 3072

typedef __attribute__((ext_vector_type(4))) float f32x4;
typedef __attribute__((ext_vector_type(8))) short s16x8;

static __device__ __forceinline__ short f2bf(float x) {
  unsigned u = __builtin_bit_cast(unsigned, x);
  unsigned r = (u + 0x7FFFu + ((u >> 16) & 1u)) >> 16;
  return (short)r;
}
static __device__ __forceinline__ float bf2f(short x) {
  unsigned u = ((unsigned)(unsigned short)x) << 16;
  return __builtin_bit_cast(float, u);
}
static __device__ __forceinline__ float bperm(int idx, float v) {
  return __builtin_bit_cast(float,
      __builtin_amdgcn_ds_bpermute(idx, __builtin_bit_cast(int, v)));
}

// ---------------------------------------------------------------------------
// Fused fp32 -> bf16 convert for all 5 tensors (one launch).
// ---------------------------------------------------------------------------
__global__ __launch_bounds__(256) void cvt_all(
    const float* __restrict__ x, const float* __restrict__ in_w,
    const float* __restrict__ pos, const float* __restrict__ pos_w,
    const float* __restrict__ out_w,
    short* __restrict__ xb, short* __restrict__ inwb, short* __restrict__ posb,
    short* __restrict__ poswb, short* __restrict__ outwb) {
  const long M1 = 1 << 20;
  long off = (long)(blockIdx.x * 256 + threadIdx.x) * 8;
  const float* src; short* dst; long nsrc;
  if (off < 2 * M1)      { src = x;     dst = xb;    nsrc = 2 * M1; }
  else if (off < 5 * M1) { off -= 2 * M1; src = in_w;  dst = inwb;  nsrc = 3 * M1; }
  else if (off < 7 * M1) { off -= 5 * M1; src = pos;   dst = posb;  nsrc = (long)RR * EE; }
  else if (off < 8 * M1) { off -= 7 * M1; src = pos_w; dst = poswb; nsrc = M1; }
  else                   { off -= 8 * M1; src = out_w; dst = outwb; nsrc = M1; }
  s16x8 o;
  if (off + 8 <= nsrc) {
    f32x4 a = *(const f32x4*)&src[off];
    f32x4 c = *(const f32x4*)&src[off + 4];
    #pragma unroll
    for (int j = 0; j < 4; ++j) { o[j] = f2bf(a[j]); o[4 + j] = f2bf(c[j]); }
  } else {
    #pragma unroll
    for (int j = 0; j < 8; ++j) o[j] = 0;
  }
  *(s16x8*)&dst[off] = o;
}

// ---------------------------------------------------------------------------
// bf16 MFMA GEMM (m97 structure): C[M,N] = A[M,K] @ W[N,K]^T + bias[N]
// ---------------------------------------------------------------------------
#define GBM 128
#define GBN 128
#define GBK 32

template <int OUT_BF16>
__global__ __launch_bounds__(256) void gemm_bf16_mfma(
    const short* __restrict__ A, const short* __restrict__ W,
    const float* __restrict__ bias, void* __restrict__ Cout,
    int M, int N, int K) {
  __shared__ __align__(16) short lA[2][GBM * GBK];
  __shared__ __align__(16) short lB[2][GBN * GBK];

  const int tid = threadIdx.x;
  const int lane = tid & 63;
  const int wv = tid >> 6;
  const int g = lane >> 4, cc = lane & 15;
  const int wr = wv >> 1, wc = wv & 1;
  const int m0 = blockIdx.y * GBM, n0 = blockIdx.x * GBN;

  f32x4 acc[4][4];
  #pragma unroll
  for (int i = 0; i < 4; ++i)
    #pragma unroll
    for (int j = 0; j < 4; ++j) acc[i][j] = (f32x4){0.f, 0.f, 0.f, 0.f};

#define STAGE_TILE(kk_, buf_)                                                  \
  {                                                                            \
    _Pragma("unroll")                                                          \
    for (int s = 0; s < 2; ++s) {                                              \
      int c = s * 256 + tid;                                                   \
      int row = c >> 2, slot = c & 3;                                          \
      int k8 = slot ^ (row & 3);                                               \
      __builtin_amdgcn_global_load_lds(                                        \
          (const __attribute__((address_space(1))) void*)(A + (size_t)(m0 + row) * K + (kk_) + k8 * 8), \
          (__attribute__((address_space(3))) void*)&lA[buf_][c * 8], 16, 0, 0);\
      __builtin_amdgcn_global_load_lds(                                        \
          (const __attribute__((address_space(1))) void*)(W + (size_t)(n0 + row) * K + (kk_) + k8 * 8), \
          (__attribute__((address_space(3))) void*)&lB[buf_][c * 8], 16, 0, 0);\
    }                                                                          \
  }

  int cur = 0;
  const int nt = K / GBK;
  STAGE_TILE(0, 0);

  #pragma unroll 1
  for (int t = 0; t < nt; ++t) {
    __syncthreads();
    if (t + 1 < nt) STAGE_TILE((t + 1) * GBK, cur ^ 1);

    s16x8 af[4], bf[4];
    #pragma unroll
    for (int mt = 0; mt < 4; ++mt) {
      int row = 64 * wr + 16 * mt + cc;
      af[mt] = *(const s16x8*)&lA[cur][row * GBK + ((g ^ (row & 3)) * 8)];
    }
    #pragma unroll
    for (int ntc = 0; ntc < 4; ++ntc) {
      int col = 64 * wc + 16 * ntc + cc;
      bf[ntc] = *(const s16x8*)&lB[cur][col * GBK + ((g ^ (col & 3)) * 8)];
    }
    #pragma unroll
    for (int mt = 0; mt < 4; ++mt)
      #pragma unroll
      for (int ntc = 0; ntc < 4; ++ntc)
        acc[mt][ntc] = __builtin_amdgcn_mfma_f32_16x16x32_bf16(
            af[mt], bf[ntc], acc[mt][ntc], 0, 0, 0);
    cur ^= 1;
  }
#undef STAGE_TILE

  #pragma unroll
  for (int ntc = 0; ntc < 4; ++ntc) {
    int col = n0 + 64 * wc + 16 * ntc + cc;
    float bv = bias[col];
    #pragma unroll
    for (int mt = 0; mt < 4; ++mt)
      #pragma unroll
      for (int r = 0; r < 4; ++r) {
        int rowg = m0 + 64 * wr + 16 * mt + 4 * g + r;
        float val = acc[mt][ntc][r] + bv;
        if (OUT_BF16)
          ((short*)Cout)[(size_t)rowg * N + col] = f2bf(val);
        else
          ((float*)Cout)[(size_t)rowg * N + col] = val;
      }
  }
}

// ---------------------------------------------------------------------------
// MFMA flash attention — R4 structure + loop-carried prefetch + bperm BD.
//   grid (T/16=64, B*H=32); 2 waves/block; both waves own the same 16 q-rows;
//   wave w handles keys [512w, 512w+512) as 16 sequential 32-key tiles with
//   private online softmax (proven best L2 pattern, R4); one merge barrier.
//   Loop-carried regs: vst (V tile), kf (K frags), pf (p frags) are consumed
//   at iter top (ds_write / AC / BD) then immediately re-loaded for tile t+1
//   — 12 global loads stay in flight under gather+softmax+PV (T14).
//   p band rotation: tile t+1 rows overlap by 16 -> pf[0]=pf[2], load 2.
//   BD gather via ds_bpermute (no LDS round-trip):
//     S[ct][r] += Btilde[ii=4g+r][16ct+cc+15-ii]
// LDS arena (11520 B), wave-private during loop:
//   sV[w]  = arena + w*4352         : short[32][68]   (loop; merge sO aliases)
//   sPm[w] = arena + 8704 + w*1280  : short[16][40]
//   sML    = arena + 11264          : float[2][2][16]
// ---------------------------------------------------------------------------
#define QB 16

__global__ __launch_bounds__(128, 3) void rel_attn_mfma5(
    const short* __restrict__ qkvb,  // [TB][3E] bf16
    const short* __restrict__ pb,    // [2048][E] bf16 (row 2047 zeroed)
    const float* __restrict__ rwb,   // [H*D]
    const float* __restrict__ rrb,   // [H*D]
    short* __restrict__ ctxb) {      // [TB][E] bf16
  __shared__ __align__(16) char arena[11520];

  const int tid = threadIdx.x;
  const int wv = tid >> 6;
  const int lane = tid & 63;
  const int g = lane >> 4;      // 0..3
  const int cc = lane & 15;     // 0..15
  const int iq0 = blockIdx.x * QB;
  const int bh = blockIdx.y;
  const int b = bh >> 4, h = bh & 15;
  const int hoff = h * DD;

  short* sV  = (short*)(arena + wv * 4352);           // [32][68]
  short* sPm = (short*)(arena + 8704 + wv * 1280);    // [16][40]

  // ---- Q fragments: row = cc (q row iq0+cc), k-pack d = 32*kh + 8*g ----
  s16x8 qw[2], qr[2];
  #pragma unroll
  for (int kh = 0; kh < 2; ++kh) {
    const int d0 = 32 * kh + 8 * g;
    const short* qp = qkvb + (size_t)((iq0 + cc) * BB + b) * E3 + hoff + d0;
    const float* rw = rwb + hoff + d0;
    const float* rr = rrb + hoff + d0;
    s16x8 qv = *(const s16x8*)qp;
    #pragma unroll
    for (int j = 0; j < 8; ++j) {
      float q = bf2f(qv[j]);
      qw[kh][j] = f2bf((q + rw[j]) * 0.125f);
      qr[kh][j] = f2bf((q + rr[j]) * 0.125f);
    }
  }

  f32x4 O[4];
  #pragma unroll
  for (int dt = 0; dt < 4; ++dt) O[dt] = (f32x4){0.f, 0.f, 0.f, 0.f};
  float mrun[4], lrun[4];
  #pragma unroll
  for (int r = 0; r < 4; ++r) { mrun[r] = -1e30f; lrun[r] = 0.f; }

  // ---- loop-carried prefetch registers (tile t data) ----
  s16x8 vst[4];        // V tile [32][64] slices, mapping id=c*64+lane
  s16x8 kf[2][2];      // K fragments
  s16x8 pf[3][2];      // p band fragments (rows gmin+16ut+cc)

  // prologue: load tile 0
  {
    const int j0 = 512 * wv;
    const int gmin = j0 - iq0 + 1008;
    #pragma unroll
    for (int c = 0; c < 4; ++c) {
      int id = c * 64 + lane;
      int row = id >> 3, c8 = id & 7;
      vst[c] = *(const s16x8*)(qkvb + (size_t)((j0 + row) * BB + b) * E3 + 2 * EE + hoff + c8 * 8);
    }
    #pragma unroll
    for (int ct = 0; ct < 2; ++ct)
      #pragma unroll
      for (int kh = 0; kh < 2; ++kh)
        kf[ct][kh] = *(const s16x8*)(qkvb + (size_t)((j0 + 16 * ct + cc) * BB + b) * E3 + EE + hoff + 32 * kh + 8 * g);
    #pragma unroll
    for (int ut = 0; ut < 3; ++ut)
      #pragma unroll
      for (int kh = 0; kh < 2; ++kh)
        pf[ut][kh] = *(const s16x8*)(pb + (size_t)(gmin + 16 * ut + cc) * EE + hoff + 32 * kh + 8 * g);
  }

  #pragma unroll 1
  for (int t = 0; t < 16; ++t) {
    // ---- commit V tile regs -> wave-private LDS ----
    #pragma unroll
    for (int c = 0; c < 4; ++c) {
      int id = c * 64 + lane;
      int row = id >> 3, c8 = id & 7;
      *(s16x8*)&sV[row * 68 + c8 * 8] = vst[c];
    }

    // ---- AC: S[ct] = qw . K^T ----
    f32x4 S[2];
    #pragma unroll
    for (int ct = 0; ct < 2; ++ct) {
      S[ct] = (f32x4){0.f, 0.f, 0.f, 0.f};
      #pragma unroll
      for (int kh = 0; kh < 2; ++kh)
        S[ct] = __builtin_amdgcn_mfma_f32_16x16x32_bf16(qw[kh], kf[ct][kh], S[ct], 0, 0, 0);
    }

    // ---- BD: Btilde = qr . pband^T (3 ut tiles) ----
    f32x4 bt[3];
    #pragma unroll
    for (int ut = 0; ut < 3; ++ut) {
      bt[ut] = (f32x4){0.f, 0.f, 0.f, 0.f};
      #pragma unroll
      for (int kh = 0; kh < 2; ++kh)
        bt[ut] = __builtin_amdgcn_mfma_f32_16x16x32_bf16(qr[kh], pf[ut][kh], bt[ut], 0, 0, 0);
    }

    // ---- prefetch tile t+1 into the just-consumed registers (T14) ----
    if (t != 15) {
      const int j0n = 512 * wv + 32 * (t + 1);
      const int gminn = j0n - iq0 + 1008;
      #pragma unroll
      for (int c = 0; c < 4; ++c) {
        int id = c * 64 + lane;
        int row = id >> 3, c8 = id & 7;
        vst[c] = *(const s16x8*)(qkvb + (size_t)((j0n + row) * BB + b) * E3 + 2 * EE + hoff + c8 * 8);
      }
      #pragma unroll
      for (int ct = 0; ct < 2; ++ct)
        #pragma unroll
        for (int kh = 0; kh < 2; ++kh)
          kf[ct][kh] = *(const s16x8*)(qkvb + (size_t)((j0n + 16 * ct + cc) * BB + b) * E3 + EE + hoff + 32 * kh + 8 * g);
      // band rotation: new rows gminn+cc == old gmin+32+cc == pf[2]
      pf[0][0] = pf[2][0];
      pf[0][1] = pf[2][1];
      #pragma unroll
      for (int ut = 1; ut < 3; ++ut)
        #pragma unroll
        for (int kh = 0; kh < 2; ++kh)
          pf[ut][kh] = *(const s16x8*)(pb + (size_t)(gminn + 16 * ut + cc) * EE + hoff + 32 * kh + 8 * g);
    }

    // ---- BD gather via bpermute: S[ct][r] += Btilde[ii][16ct+cc+15-ii] ----
    #pragma unroll
    for (int r = 0; r < 4; ++r) {
      const int usub = cc + 15 - 4 * g - r;            // 0..30
      const int idx = ((lane & 48) | (usub & 15)) << 2;
      const float va = bperm(idx, bt[0][r]);
      const float vb = bperm(idx, bt[1][r]);
      const float vc = bperm(idx, bt[2][r]);
      const bool hi = usub >= 16;
      S[0][r] += hi ? vb : va;
      S[1][r] += hi ? vc : vb;
    }

    // ---- online softmax (rows = 4g+r, cols spread over cc and ct) ----
    float mx[4];
    #pragma unroll
    for (int r = 0; r < 4; ++r) mx[r] = fmaxf(S[0][r], S[1][r]);
    #pragma unroll
    for (int msk = 1; msk < 16; msk <<= 1)
      #pragma unroll
      for (int r = 0; r < 4; ++r) mx[r] = fmaxf(mx[r], __shfl_xor(mx[r], msk, 64));
    float f[4], sm[4];
    #pragma unroll
    for (int r = 0; r < 4; ++r) {
      float mn = fmaxf(mrun[r], mx[r]);
      f[r] = __expf(mrun[r] - mn);
      mrun[r] = mn;
      S[0][r] = __expf(S[0][r] - mn);
      S[1][r] = __expf(S[1][r] - mn);
      sm[r] = S[0][r] + S[1][r];
    }
    #pragma unroll
    for (int msk = 1; msk < 16; msk <<= 1)
      #pragma unroll
      for (int r = 0; r < 4; ++r) sm[r] += __shfl_xor(sm[r], msk, 64);
    #pragma unroll
    for (int r = 0; r < 4; ++r) lrun[r] = lrun[r] * f[r] + sm[r];
    #pragma unroll
    for (int dt = 0; dt < 4; ++dt)
      #pragma unroll
      for (int r = 0; r < 4; ++r) O[dt][r] *= f[r];

    // ---- P to A-fragment layout via wave-private LDS ----
    #pragma unroll
    for (int ct = 0; ct < 2; ++ct)
      #pragma unroll
      for (int r = 0; r < 4; ++r)
        sPm[(4 * g + r) * 40 + 16 * ct + cc] = f2bf(S[ct][r]);

    s16x8 pa = *(const s16x8*)&sPm[cc * 40 + 8 * g];

    // ---- V^T fragments (scalar transpose reads) + PV ----
    s16x8 vf[4];
    #pragma unroll
    for (int dt = 0; dt < 4; ++dt)
      #pragma unroll
      for (int jj = 0; jj < 8; ++jj)
        vf[dt][jj] = sV[(8 * g + jj) * 68 + 16 * dt + cc];
    #pragma unroll
    for (int dt = 0; dt < 4; ++dt)
      O[dt] = __builtin_amdgcn_mfma_f32_16x16x32_bf16(pa, vf[dt], O[dt], 0, 0, 0);
  }

  // ---- merge the two waves' partial (O, m, l) ----
  float* sO0 = (float*)(arena);                 // wave0 O  [16][68]
  float* sO1 = (float*)(arena + 4352);          // wave1 O  [16][68]
  float* sML = (float*)(arena + 11264);         // [w][2][16]
  float* sOw = wv ? sO1 : sO0;
  #pragma unroll
  for (int dt = 0; dt < 4; ++dt)
    #pragma unroll
    for (int r = 0; r < 4; ++r)
      sOw[(4 * g + r) * 68 + 16 * dt + cc] = O[dt][r];
  if (cc == 0) {
    #pragma unroll
    for (int r = 0; r < 4; ++r) {
      sML[wv * 32 + (4 * g + r)] = mrun[r];
      sML[wv * 32 + 16 + (4 * g + r)] = lrun[r];
    }
  }
  __syncthreads();

  #pragma unroll
  for (int r = 0; r < 4; ++r) {
    const int ii = 4 * g + r;
    const float m0 = sML[ii], l0 = sML[16 + ii];
    const float m1 = sML[32 + ii], l1 = sML[48 + ii];
    const float M = fmaxf(m0, m1);
    const float f0 = __expf(m0 - M), f1 = __expf(m1 - M);
    const float rinv = 1.0f / (f0 * l0 + f1 * l1);
    #pragma unroll
    for (int dt2 = 0; dt2 < 2; ++dt2) {
      const int dt = 2 * wv + dt2;
      const int col = 16 * dt + cc;
      const float val = (f0 * sO0[ii * 68 + col] + f1 * sO1[ii * 68 + col]) * rinv;
      ctxb[(size_t)((iq0 + ii) * BB + b) * EE + hoff + col] = f2bf(val);
    }
  }
}

// ---------------------------------------------------------------------------
extern "C" void kernel_launch(void* const* d_in, const int* in_sizes, int n_in,
                              void* d_out, int out_size, void* d_ws, size_t ws_size,
                              hipStream_t stream) {
  const float* x      = (const float*)d_in[0];
  const float* pos    = (const float*)d_in[1];
  const float* in_w   = (const float*)d_in[2];
  const float* in_b   = (const float*)d_in[3];
  const float* pos_w  = (const float*)d_in[4];
  const float* pos_b  = (const float*)d_in[5];
  const float* out_w  = (const float*)d_in[6];
  const float* out_b  = (const float*)d_in[7];
  const float* r_w    = (const float*)d_in[8];
  const float* r_r    = (const float*)d_in[9];
  float* out = (float*)d_out;

  const size_t M1 = 1024 * 1024;
  short* xb    = (short*)d_ws;        // 2M
  short* inwb  = xb    + 2 * M1;      // 3M
  short* posb  = inwb  + 3 * M1;      // 2M (2048 rows, row 2047 zeroed)
  short* poswb = posb  + 2 * M1;      // 1M
  short* outwb = poswb + 1 * M1;      // 1M
  short* qkvb  = outwb + 1 * M1;      // 6M
  short* pb    = qkvb  + 6 * M1;      // 2M
  short* ctxb  = pb    + 2 * M1;      // 2M

  cvt_all<<<dim3(4608), dim3(256), 0, stream>>>(
      x, in_w, pos, pos_w, out_w, xb, inwb, posb, poswb, outwb);

  gemm_bf16_mfma<1><<<dim3(E3 / GBN, TB / GBM), dim3(256), 0, stream>>>(
      xb, inwb, in_b, qkvb, TB, E3, EE);

  gemm_bf16_mfma<1><<<dim3(EE / GBN, 2048 / GBM), dim3(256), 0, stream>>>(
      posb, poswb, pos_b, pb, 2048, EE, EE);

  rel_attn_mfma5<<<dim3(TT / QB, BB * HH), dim3(128), 0, stream>>>(
      qkvb, pb, r_w, r_r, ctxb);

  gemm_bf16_mfma<0><<<dim3(EE / GBN, TB / GBM), dim3(256), 0, stream>>>(
      ctxb, outwb, out_b, out, TB, EE, EE);
}